// Round 13
// baseline (68.308 us; speedup 1.0000x reference)
//
#include <hip/hip_runtime.h>

typedef float v2f __attribute__((ext_vector_type(2)));

#define B_   16
#define C_   3
#define H_   64
#define W_   64
#define K_   32
#define S_   16
#define OH_  60
#define OW_  60
#define P_   3600

#define KG   4                  // k's per block (one per wave)
#define NKG  (K_/KG)            // 8 k-groups
#define NBQ  4                  // batch-quarters (4 batches per block)
#define ROWS (C_*5)             // 15 (c, rh) rows per oh-stripe
#define BP   4                  // batches staged per block
#define ROWSTRIDE (W_*BP)       // 256 floats
#define XLDS (ROWS*ROWSTRIDE)   // 3840 floats = 15.36 KB

// Packed 2-batch gate: c0 + c1*a + c2*b + c3*a*b over a float2 lane-pair.
// Targets v_pk_fma_f32 (VOP3P); 3 pk-FMA replace 6 scalar FMA.
__device__ __forceinline__ v2f gate2(float4 c, v2f a, v2f b) {
    v2f cx = {c.x, c.x}, cy = {c.y, c.y}, cz = {c.z, c.z}, cw = {c.w, c.w};
    return __builtin_elementwise_fma(__builtin_elementwise_fma(cw, a, cz), b,
                                     __builtin_elementwise_fma(cy, a, cx));
}

// ---------------- prep: coefs (992 softmax@M) + base offsets, ONCE ---------
// R12 recomputed these in every one of 1920 blocks (238K softmaxes vs 992
// needed) — a large share of the measured ~10us VALU-issue time.
__global__ __launch_bounds__(256) void prep_kernel(
    const int* __restrict__ ah, const int* __restrict__ aw, const int* __restrict__ ac,
    const int* __restrict__ bh, const int* __restrict__ bw, const int* __restrict__ bc,
    const float* __restrict__ w0, const float* __restrict__ w1,
    const float* __restrict__ w2, const float* __restrict__ w3,
    const float* __restrict__ w4,
    float4* __restrict__ cfg, int* __restrict__ bAg, int* __restrict__ bBg)
{
    const int blk = blockIdx.x, tid = threadIdx.x;
    if (blk < 4) {
        int t = blk * 256 + tid;
        if (t >= 31 * K_) return;
        int node = t >> 5, k = t & 31;
        const float* w; int i;
        if      (node < 16) { w = w0; i = node;      }
        else if (node < 24) { w = w1; i = node - 16; }
        else if (node < 28) { w = w2; i = node - 24; }
        else if (node < 30) { w = w3; i = node - 28; }
        else                { w = w4; i = 0;         }
        const float* src = w + ((size_t)i * K_ + k) * 16;
        float lg[16];
        float m = -1e30f;
#pragma unroll
        for (int s = 0; s < 16; ++s) { lg[s] = src[s]; m = fmaxf(m, lg[s]); }
        float sum = 0.f;
#pragma unroll
        for (int s = 0; s < 16; ++s) { lg[s] = expf(lg[s] - m); sum += lg[s]; }
        float inv = 1.f / sum;
        const float M[16][4] = {
            {0,0,0,0},{0,0,0,1},{0,1,0,-1},{0,1,0,0},
            {0,0,1,-1},{0,0,1,0},{0,1,1,-2},{0,1,1,-1},
            {1,-1,-1,1},{1,-1,-1,2},{1,0,-1,0},{1,0,-1,1},
            {1,-1,0,0},{1,-1,0,1},{1,0,0,-1},{1,0,0,0}};
        float c0 = 0.f, c1 = 0.f, c2 = 0.f, c3 = 0.f;
#pragma unroll
        for (int s = 0; s < 16; ++s) {
            float pr = lg[s] * inv;
            c0 += pr * M[s][0]; c1 += pr * M[s][1];
            c2 += pr * M[s][2]; c3 += pr * M[s][3];
        }
        cfg[k * 31 + node] = make_float4(c0, c1, c2, c3);
    } else {
#pragma unroll
        for (int rep = 0; rep < 4; ++rep) {
            int idx = rep * 256 + tid;       // 0..1023
            if (idx < 512) {
                int k = idx >> 4, s = idx & 15;
                int j = k * (P_ * 16) + s;   // p = 0 slice
                bAg[idx] = (ac[j] * 5 + ah[j]) * ROWSTRIDE + aw[j] * BP;
            } else {
                int i2 = idx - 512;
                int k = i2 >> 4, s = i2 & 15;
                int j = k * (P_ * 16) + s;
                bBg[i2] = (bc[j] * 5 + bh[j]) * ROWSTRIDE + bw[j] * BP;
            }
        }
    }
}

// ---------------- main: stage + packed gate tree ---------------------------
__global__ __launch_bounds__(256, 4) void logic_main_kernel(
    const float* __restrict__ x, const float4* __restrict__ cfg,
    const int* __restrict__ bAg, const int* __restrict__ bBg,
    float* __restrict__ out)
{
    __shared__ float  xs[XLDS];
    __shared__ float4 cf[KG * 31];
    __shared__ int    bAi[KG * S_], bBi[KG * S_];

    const int oh  = blockIdx.x;
    const int bq  = blockIdx.y;
    const int kg  = blockIdx.z;
    const int tid = threadIdx.x;
    const int l   = tid & 63;
    const int wv  = tid >> 6;            // 0..3

    // ---- stage x: 60 jobs; lane = (w0 = l>>2, b = l&3)
    {
        const int b  = l & 3;
        const int w0 = l >> 2;           // 0..15
        const int gb = bq * 4 + b;
        for (int job = wv; job < ROWS * 4; job += 4) {
            int wb  = job & 3;
            int row = job >> 2;          // 0..14 = c*5 + dh
            int c   = row >= 10 ? 2 : (row >= 5 ? 1 : 0);
            int dh  = row - 5 * c;
            int w   = w0 + 16 * wb;
            xs[row * ROWSTRIDE + w * BP + b] =
                x[((gb * C_ + c) * H_ + (oh + dh)) * W_ + w];
        }
    }
    // ---- copy precomputed coefs + bases into LDS (cheap L2 reads)
    if (tid < 128) {
        int kk = tid >> 5, node = tid & 31;
        if (node < 31)
            cf[kk * 31 + node] = cfg[(kg * KG + kk) * 31 + node];
    } else {
        int i = tid - 128;               // 0..127
        if (i < 64) {
            int k = kg * KG + (i >> 4);
            bAi[i] = bAg[k * 16 + (i & 15)];
        } else {
            int i2 = i - 64;
            int k = kg * KG + (i2 >> 4);
            bBi[i2] = bBg[k * 16 + (i2 & 15)];
        }
    }
    __syncthreads();

    // ---- compute: wave wv -> k = kg*4 + wv; lane = ow
    const int k      = kg * KG + wv;
    const int ow     = l;
    const int ow_eff = ow < OW_ ? ow : OW_ - 1;   // helpers clamp (broadcast)
    const int lo     = ow_eff * BP;

    int baseA[S_], baseB[S_];            // wave-uniform -> SGPR
#pragma unroll
    for (int s = 0; s < S_; ++s) {
        baseA[s] = __builtin_amdgcn_readfirstlane(bAi[wv * 16 + s]);
        baseB[s] = __builtin_amdgcn_readfirstlane(bBi[wv * 16 + s]);
    }

    const float4* cfw = &cf[wv * 31];

    v2f t0[8], t1[8];                    // level-1 outputs, batch pairs 01/23
#pragma unroll
    for (int g = 0; g < 4; ++g) {        // 4 leaves per group: 8 reads in flight
        float4 A[4], Bv[4];
#pragma unroll
        for (int m = 0; m < 4; ++m) {
            A[m]  = *(const float4*)&xs[baseA[4*g + m] + lo];
            Bv[m] = *(const float4*)&xs[baseB[4*g + m] + lo];
        }
#pragma unroll
        for (int m = 0; m < 2; ++m) {
            const int s0 = 2 * m;        // within group
            const int n1 = 2 * g + m;    // level-1 node 0..7
            float4 c0 = cfw[4*g + s0], c1 = cfw[4*g + s0 + 1], d = cfw[16 + n1];
            v2f a0l = {A[s0].x,  A[s0].y},   a0h = {A[s0].z,  A[s0].w};
            v2f b0l = {Bv[s0].x, Bv[s0].y},  b0h = {Bv[s0].z, Bv[s0].w};
            v2f a1l = {A[s0+1].x, A[s0+1].y}, a1h = {A[s0+1].z, A[s0+1].w};
            v2f b1l = {Bv[s0+1].x,Bv[s0+1].y},b1h = {Bv[s0+1].z,Bv[s0+1].w};
            v2f l0l = gate2(c0, a0l, b0l), l0h = gate2(c0, a0h, b0h);
            v2f l1l = gate2(c1, a1l, b1l), l1h = gate2(c1, a1h, b1h);
            t0[n1] = gate2(d, l0l, l1l);
            t1[n1] = gate2(d, l0h, l1h);
        }
    }
#pragma unroll
    for (int i = 0; i < 4; ++i) {        // level 2
        float4 c = cfw[24 + i];
        t0[i] = gate2(c, t0[2*i], t0[2*i+1]);
        t1[i] = gate2(c, t1[2*i], t1[2*i+1]);
    }
#pragma unroll
    for (int i = 0; i < 2; ++i) {        // level 3
        float4 c = cfw[28 + i];
        t0[i] = gate2(c, t0[2*i], t0[2*i+1]);
        t1[i] = gate2(c, t1[2*i], t1[2*i+1]);
    }
    {
        float4 c = cfw[30];              // root
        v2f r0 = gate2(c, t0[0], t0[1]);
        v2f r1 = gate2(c, t1[0], t1[1]);
        if (ow < OW_) {
            const size_t obase = (size_t)k * P_ + oh * OW_ + ow;
            out[(size_t)(bq*4 + 0) * (K_*P_) + obase] = r0.x;
            out[(size_t)(bq*4 + 1) * (K_*P_) + obase] = r0.y;
            out[(size_t)(bq*4 + 2) * (K_*P_) + obase] = r1.x;
            out[(size_t)(bq*4 + 3) * (K_*P_) + obase] = r1.y;
        }
    }
}

extern "C" void kernel_launch(void* const* d_in, const int* in_sizes, int n_in,
                              void* d_out, int out_size, void* d_ws, size_t ws_size,
                              hipStream_t stream) {
    const float* x  = (const float*)d_in[0];
    const int* ah = (const int*)d_in[1];
    const int* aw = (const int*)d_in[2];
    const int* ac = (const int*)d_in[3];
    const int* bh = (const int*)d_in[4];
    const int* bw = (const int*)d_in[5];
    const int* bc = (const int*)d_in[6];
    const float* w0 = (const float*)d_in[7];
    const float* w1 = (const float*)d_in[8];
    const float* w2 = (const float*)d_in[9];
    const float* w3 = (const float*)d_in[10];
    const float* w4 = (const float*)d_in[11];
    float* out = (float*)d_out;

    float4* cfg = (float4*)d_ws;                    // 992 float4 = 15.9 KB
    int*    bAg = (int*)(cfg + 31 * K_);            // 512 ints
    int*    bBg = bAg + K_ * S_;                    // 512 ints

    prep_kernel<<<5, 256, 0, stream>>>(ah, aw, ac, bh, bw, bc,
                                       w0, w1, w2, w3, w4, cfg, bAg, bBg);

    dim3 grid(OH_, NBQ, NKG);
    logic_main_kernel<<<grid, 256, 0, stream>>>(x, cfg, bAg, bBg, out);
}

// Round 14
// 51.234 us; speedup vs baseline: 1.3332x; 1.3332x over previous
//
#include <hip/hip_runtime.h>

typedef float v2f __attribute__((ext_vector_type(2)));

#define B_   16
#define C_   3
#define H_   64
#define W_   64
#define K_   32
#define S_   16
#define OH_  60
#define OW_  60
#define P_   3600

#define KG   4                  // k's per block (one per wave)
#define NKG  (K_/KG)            // 8 k-groups
#define NBQ  4                  // batch-quarters (4 batches per block)
#define ROWS (C_*5)             // 15 (c, rh) rows per oh-stripe
#define BP   4                  // batches staged per block
#define ROWSTRIDE (W_*BP)       // 256 floats
#define XLDS (ROWS*ROWSTRIDE)   // 3840 floats = 15.36 KB

// Packed 2-batch gate: 3 v_pk_fma_f32 per gate (2 batches).
__device__ __forceinline__ v2f gate2(float4 c, v2f a, v2f b) {
    v2f cx = {c.x, c.x}, cy = {c.y, c.y}, cz = {c.z, c.z}, cw = {c.w, c.w};
    return __builtin_elementwise_fma(__builtin_elementwise_fma(cw, a, cz), b,
                                     __builtin_elementwise_fma(cy, a, cx));
}

// ---------------- prep: coefs (992 softmax@M) + base offsets, ONCE ---------
__global__ __launch_bounds__(256) void prep_kernel(
    const int* __restrict__ ah, const int* __restrict__ aw, const int* __restrict__ ac,
    const int* __restrict__ bh, const int* __restrict__ bw, const int* __restrict__ bc,
    const float* __restrict__ w0, const float* __restrict__ w1,
    const float* __restrict__ w2, const float* __restrict__ w3,
    const float* __restrict__ w4,
    float4* __restrict__ cfg, int* __restrict__ bAg, int* __restrict__ bBg)
{
    const int blk = blockIdx.x, tid = threadIdx.x;
    if (blk < 4) {
        int t = blk * 256 + tid;
        if (t >= 31 * K_) return;
        int node = t >> 5, k = t & 31;
        const float* w; int i;
        if      (node < 16) { w = w0; i = node;      }
        else if (node < 24) { w = w1; i = node - 16; }
        else if (node < 28) { w = w2; i = node - 24; }
        else if (node < 30) { w = w3; i = node - 28; }
        else                { w = w4; i = 0;         }
        const float* src = w + ((size_t)i * K_ + k) * 16;
        float lg[16];
        float m = -1e30f;
#pragma unroll
        for (int s = 0; s < 16; ++s) { lg[s] = src[s]; m = fmaxf(m, lg[s]); }
        float sum = 0.f;
#pragma unroll
        for (int s = 0; s < 16; ++s) { lg[s] = expf(lg[s] - m); sum += lg[s]; }
        float inv = 1.f / sum;
        const float M[16][4] = {
            {0,0,0,0},{0,0,0,1},{0,1,0,-1},{0,1,0,0},
            {0,0,1,-1},{0,0,1,0},{0,1,1,-2},{0,1,1,-1},
            {1,-1,-1,1},{1,-1,-1,2},{1,0,-1,0},{1,0,-1,1},
            {1,-1,0,0},{1,-1,0,1},{1,0,0,-1},{1,0,0,0}};
        float c0 = 0.f, c1 = 0.f, c2 = 0.f, c3 = 0.f;
#pragma unroll
        for (int s = 0; s < 16; ++s) {
            float pr = lg[s] * inv;
            c0 += pr * M[s][0]; c1 += pr * M[s][1];
            c2 += pr * M[s][2]; c3 += pr * M[s][3];
        }
        cfg[k * 31 + node] = make_float4(c0, c1, c2, c3);
    } else {
#pragma unroll
        for (int rep = 0; rep < 4; ++rep) {
            int idx = rep * 256 + tid;       // 0..1023
            if (idx < 512) {
                int k = idx >> 4, s = idx & 15;
                int j = k * (P_ * 16) + s;   // p = 0 slice
                bAg[idx] = (ac[j] * 5 + ah[j]) * ROWSTRIDE + aw[j] * BP;
            } else {
                int i2 = idx - 512;
                int k = i2 >> 4, s = i2 & 15;
                int j = k * (P_ * 16) + s;
                bBg[i2] = (bc[j] * 5 + bh[j]) * ROWSTRIDE + bw[j] * BP;
            }
        }
    }
}

// level-1 subtree: leaves 2i,2i+1 -> node 16+i (batch pairs 01 / 23)
__device__ __forceinline__ void leafpair(
    const float* __restrict__ xs, const float4* __restrict__ cfw,
    const int* baseA, const int* baseB, int lo, int i,
    v2f& out_lo, v2f& out_hi)
{
    const int s0 = 2 * i, s1 = 2 * i + 1;
    float4 A0 = *(const float4*)&xs[baseA[s0] + lo];
    float4 B0 = *(const float4*)&xs[baseB[s0] + lo];
    float4 A1 = *(const float4*)&xs[baseA[s1] + lo];
    float4 B1 = *(const float4*)&xs[baseB[s1] + lo];
    float4 c0 = cfw[s0], c1 = cfw[s1], d = cfw[16 + i];
    v2f l0l = gate2(c0, (v2f){A0.x, A0.y}, (v2f){B0.x, B0.y});
    v2f l0h = gate2(c0, (v2f){A0.z, A0.w}, (v2f){B0.z, B0.w});
    v2f l1l = gate2(c1, (v2f){A1.x, A1.y}, (v2f){B1.x, B1.y});
    v2f l1h = gate2(c1, (v2f){A1.z, A1.w}, (v2f){B1.z, B1.w});
    out_lo = gate2(d, l0l, l1l);
    out_hi = gate2(d, l0h, l1h);
}

// ---------------- main: stage + DFS packed gate tree -----------------------
// amdgpu_waves_per_eu(4,4): pins the allocator's occupancy target at 4
// waves/EU -> 128-VGPR budget. (R13 lesson: with only launch_bounds, the
// backend targeted the LDS-derived 8 waves/EU -> 64-VGPR cap -> ~190MB of
// scratch traffic.) DFS evaluation keeps peak live state ~40-50 VGPRs.
__global__ __launch_bounds__(256)
__attribute__((amdgpu_waves_per_eu(4, 4))) void logic_main_kernel(
    const float* __restrict__ x, const float4* __restrict__ cfg,
    const int* __restrict__ bAg, const int* __restrict__ bBg,
    float* __restrict__ out)
{
    __shared__ float  xs[XLDS];
    __shared__ float4 cf[KG * 31];
    __shared__ int    bAi[KG * S_], bBi[KG * S_];

    const int oh  = blockIdx.x;
    const int bq  = blockIdx.y;
    const int kg  = blockIdx.z;
    const int tid = threadIdx.x;
    const int l   = tid & 63;
    const int wv  = tid >> 6;            // 0..3

    // ---- stage x: 60 jobs; lane = (w0 = l>>2, b = l&3)
    {
        const int b  = l & 3;
        const int w0 = l >> 2;           // 0..15
        const int gb = bq * 4 + b;
        for (int job = wv; job < ROWS * 4; job += 4) {
            int wb  = job & 3;
            int row = job >> 2;          // 0..14 = c*5 + dh
            int c   = row >= 10 ? 2 : (row >= 5 ? 1 : 0);
            int dh  = row - 5 * c;
            int w   = w0 + 16 * wb;
            xs[row * ROWSTRIDE + w * BP + b] =
                x[((gb * C_ + c) * H_ + (oh + dh)) * W_ + w];
        }
    }
    // ---- copy precomputed coefs + bases into LDS (cheap L2 reads)
    if (tid < 128) {
        int kk = tid >> 5, node = tid & 31;
        if (node < 31)
            cf[kk * 31 + node] = cfg[(kg * KG + kk) * 31 + node];
    } else {
        int i = tid - 128;               // 0..127
        if (i < 64) {
            int k = kg * KG + (i >> 4);
            bAi[i] = bAg[k * 16 + (i & 15)];
        } else {
            int i2 = i - 64;
            int k = kg * KG + (i2 >> 4);
            bBi[i2] = bBg[k * 16 + (i2 & 15)];
        }
    }
    __syncthreads();

    // ---- compute: wave wv -> k = kg*4 + wv; lane = ow
    const int k      = kg * KG + wv;
    const int ow     = l;
    const int ow_eff = ow < OW_ ? ow : OW_ - 1;   // helpers clamp (broadcast)
    const int lo     = ow_eff * BP;

    int baseA[S_], baseB[S_];            // wave-uniform -> SGPR
#pragma unroll
    for (int s = 0; s < S_; ++s) {
        baseA[s] = __builtin_amdgcn_readfirstlane(bAi[wv * 16 + s]);
        baseB[s] = __builtin_amdgcn_readfirstlane(bBi[wv * 16 + s]);
    }

    const float4* cfw = &cf[wv * 31];

    // ---- DFS tree: left half -> n28, right half -> n29, root
    v2f a_lo, a_hi, b_lo, b_hi;
    leafpair(xs, cfw, baseA, baseB, lo, 0, a_lo, a_hi);
    leafpair(xs, cfw, baseA, baseB, lo, 1, b_lo, b_hi);
    float4 c24 = cfw[24];
    v2f n24l = gate2(c24, a_lo, b_lo), n24h = gate2(c24, a_hi, b_hi);

    leafpair(xs, cfw, baseA, baseB, lo, 2, a_lo, a_hi);
    leafpair(xs, cfw, baseA, baseB, lo, 3, b_lo, b_hi);
    float4 c25 = cfw[25];
    v2f n25l = gate2(c25, a_lo, b_lo), n25h = gate2(c25, a_hi, b_hi);

    float4 c28 = cfw[28];
    v2f n28l = gate2(c28, n24l, n25l), n28h = gate2(c28, n24h, n25h);

    leafpair(xs, cfw, baseA, baseB, lo, 4, a_lo, a_hi);
    leafpair(xs, cfw, baseA, baseB, lo, 5, b_lo, b_hi);
    float4 c26 = cfw[26];
    v2f n26l = gate2(c26, a_lo, b_lo), n26h = gate2(c26, a_hi, b_hi);

    leafpair(xs, cfw, baseA, baseB, lo, 6, a_lo, a_hi);
    leafpair(xs, cfw, baseA, baseB, lo, 7, b_lo, b_hi);
    float4 c27 = cfw[27];
    v2f n27l = gate2(c27, a_lo, b_lo), n27h = gate2(c27, a_hi, b_hi);

    float4 c29 = cfw[29];
    v2f n29l = gate2(c29, n26l, n27l), n29h = gate2(c29, n26h, n27h);

    float4 c30 = cfw[30];
    v2f rl = gate2(c30, n28l, n29l), rh = gate2(c30, n28h, n29h);

    if (ow < OW_) {
        const size_t obase = (size_t)k * P_ + oh * OW_ + ow;
        out[(size_t)(bq*4 + 0) * (K_*P_) + obase] = rl.x;
        out[(size_t)(bq*4 + 1) * (K_*P_) + obase] = rl.y;
        out[(size_t)(bq*4 + 2) * (K_*P_) + obase] = rh.x;
        out[(size_t)(bq*4 + 3) * (K_*P_) + obase] = rh.y;
    }
}

extern "C" void kernel_launch(void* const* d_in, const int* in_sizes, int n_in,
                              void* d_out, int out_size, void* d_ws, size_t ws_size,
                              hipStream_t stream) {
    const float* x  = (const float*)d_in[0];
    const int* ah = (const int*)d_in[1];
    const int* aw = (const int*)d_in[2];
    const int* ac = (const int*)d_in[3];
    const int* bh = (const int*)d_in[4];
    const int* bw = (const int*)d_in[5];
    const int* bc = (const int*)d_in[6];
    const float* w0 = (const float*)d_in[7];
    const float* w1 = (const float*)d_in[8];
    const float* w2 = (const float*)d_in[9];
    const float* w3 = (const float*)d_in[10];
    const float* w4 = (const float*)d_in[11];
    float* out = (float*)d_out;

    float4* cfg = (float4*)d_ws;                    // 992 float4 = 15.9 KB
    int*    bAg = (int*)(cfg + 31 * K_);            // 512 ints
    int*    bBg = bAg + K_ * S_;                    // 512 ints

    prep_kernel<<<5, 256, 0, stream>>>(ah, aw, ac, bh, bw, bc,
                                       w0, w1, w2, w3, w4, cfg, bAg, bBg);

    dim3 grid(OH_, NBQ, NKG);
    logic_main_kernel<<<grid, 256, 0, stream>>>(x, cfg, bAg, bBg, out);
}